// Round 2
// baseline (74.259 us; speedup 1.0000x reference)
//
#include <hip/hip_runtime.h>
#include <math.h>

// Problem: predict_pc 4x3x4096, gt_pc 4x3x4096 fp32; symmetric 1-NN chamfer mean.
// Inner-loop math: min d2 = p2+g2-2*p.g  <=>  max score = p.g - g2/2.
// R5: inner loop packed via v_pk_fma_f32 (VOP3P dual-fp32 FMA): candidates staged
// in LDS as pair-SoA {x0x1 y0y1 z0z1 w0w1}, points broadcast to (p,p) once.
// 6 pk_fma + 2 v_max3 per 4 pairs = 2.0 instr/pair (was 3.5). Bitwise-identical
// fma nesting; max is exact -> absmax stays 0. Pass2 unchanged (output bits).
#define BATCH 4
#define NPTS 4096
#define THREADS 256
#define P 4                          // points per thread
#define SEGS 32                      // candidate segments
#define CSEG (NPTS / SEGS)           // 128 candidates per segment
#define PTSPB (THREADS * P)          // 1024 points per block
#define PTGRPS (NPTS / PTSPB)        // 4 point-groups per (dir,batch)
#define PASS1_BLOCKS (2 * BATCH * PTGRPS * SEGS)  // 1024 -> 4 blocks/CU
#define TOTAL_PTS (2 * BATCH * NPTS)         // 32768
#define PASS2_BLOCKS 128                     // one point per thread

#define EPS 1e-8f
#define BIG 1e30f

#define PMIN_FLOATS ((size_t)SEGS * TOTAL_PTS)

typedef float f32x2 __attribute__((ext_vector_type(2)));

// v_pk_fma_f32: d.lo = fma(a.lo,b.lo,c.lo); d.hi = fma(a.hi,b.hi,c.hi)
__device__ __forceinline__ f32x2 pkfma(f32x2 a, f32x2 b, f32x2 c) {
    f32x2 d;
    asm("v_pk_fma_f32 %0, %1, %2, %3" : "=v"(d) : "v"(a), "v"(b), "v"(c));
    return d;
}

__global__ __launch_bounds__(THREADS) void chamfer_pass1(
    const float* __restrict__ pred, const float* __restrict__ gt,
    float* __restrict__ pmin, unsigned* __restrict__ cnt)
{
    // Pair-SoA candidate staging: for pair q (cands 2q,2q+1):
    //   lc4[2q]   = {x0, x1, y0, y1}
    //   lc4[2q+1] = {z0, z1, w0, w1}   (w = -0.5*g2)
    __shared__ float4 lc4[CSEG];

    const int bid   = blockIdx.x;
    if (bid == 0 && threadIdx.x == 0) *cnt = 0u;   // arm pass2's last-block flag

    const int seg   = bid & (SEGS - 1);
    const int ptgrp = (bid >> 5) & (PTGRPS - 1);
    const int batch = (bid >> 7) & (BATCH - 1);
    const int dir   = bid >> 9;

    const float* pts  = (dir == 0) ? pred : gt;
    const float* cand = (dir == 0) ? gt   : pred;

    if (threadIdx.x < CSEG) {
        const float* cb = cand + (size_t)batch * 3 * NPTS + seg * CSEG;
        const float x = cb[threadIdx.x];
        const float y = cb[NPTS + threadIdx.x];
        const float z = cb[2 * NPTS + threadIdx.x];
        const float w = -0.5f * fmaf(x, x, fmaf(y, y, z * z));
        float* lcf = (float*)lc4;
        const int q = threadIdx.x >> 1, h = threadIdx.x & 1;
        lcf[q * 8 + 0 + h] = x;
        lcf[q * 8 + 2 + h] = y;
        lcf[q * 8 + 4 + h] = z;
        lcf[q * 8 + 6 + h] = w;
    }
    __syncthreads();

    // This thread's 4 points (coalesced, stride-256 within the 1024-pt group).
    const float* pb = pts + (size_t)batch * 3 * NPTS;
    const int pbase = ptgrp * PTSPB + threadIdx.x;
    float px[P], py[P], pz[P], sx[P], sy[P];
    f32x2 px2[P], py2[P], pz2[P];
    #pragma unroll
    for (int k = 0; k < P; ++k) {
        const int i = pbase + k * THREADS;
        px[k] = pb[i];
        py[k] = pb[NPTS + i];
        pz[k] = pb[2 * NPTS + i];
        px2[k] = (f32x2){px[k], px[k]};   // loop-invariant broadcast pairs
        py2[k] = (f32x2){py[k], py[k]};
        pz2[k] = (f32x2){pz[k], pz[k]};
        sx[k] = -BIG;
        sy[k] = -BIG;
    }

    // 32 groups of 4 candidates (2 packed pairs): 4 ds_read_b128 (broadcast)
    // + P*(6 v_pk_fma_f32 + 2 v_max3_f32) per group.
    #pragma unroll 4
    for (int g = 0; g < CSEG / 4; ++g) {
        const float4 r0 = lc4[4 * g + 0];   // pair a: x0x1 y0y1
        const float4 r1 = lc4[4 * g + 1];   //         z0z1 w0w1
        const float4 r2 = lc4[4 * g + 2];   // pair b
        const float4 r3 = lc4[4 * g + 3];
        const f32x2 cxa = {r0.x, r0.y}, cya = {r0.z, r0.w};
        const f32x2 cza = {r1.x, r1.y}, cwa = {r1.z, r1.w};
        const f32x2 cxb = {r2.x, r2.y}, cyb = {r2.z, r2.w};
        const f32x2 czb = {r3.x, r3.y}, cwb = {r3.z, r3.w};
        #pragma unroll
        for (int k = 0; k < P; ++k) {
            const f32x2 ta = pkfma(px2[k], cxa, pkfma(py2[k], cya, pkfma(pz2[k], cza, cwa)));
            const f32x2 tb = pkfma(px2[k], cxb, pkfma(py2[k], cyb, pkfma(pz2[k], czb, cwb)));
            // v_max3-friendly: max over {ta,tb} halves into split accumulators
            sx[k] = fmaxf(fmaxf(ta.x, tb.x), sx[k]);
            sy[k] = fmaxf(fmaxf(ta.y, tb.y), sy[k]);
        }
    }

    // Convert back to d2 and store: pmin[seg][global_point], coalesced per k.
    const int gp = dir * (BATCH * NPTS) + batch * NPTS + pbase;
    #pragma unroll
    for (int k = 0; k < P; ++k) {
        const float smax = fmaxf(sx[k], sy[k]);   // max over same 128 scores: exact
        const float p2 = fmaf(px[k], px[k], fmaf(py[k], py[k], pz[k] * pz[k]));
        pmin[(size_t)seg * TOTAL_PTS + gp + k * THREADS] = fmaf(-2.0f, smax, p2);
    }
}

// Pass 2: one point per thread; min over 32 segment d2s, clamp, sqrt(+eps),
// block-sum; the LAST block to finish reduces the 128 block sums (identical
// shuffle tree -> identical arithmetic order) and writes the mean.
__global__ __launch_bounds__(THREADS) void chamfer_pass2(
    const float* __restrict__ pmin, float* __restrict__ bsum,
    unsigned* __restrict__ cnt, float* __restrict__ out)
{
    __shared__ float wsum[THREADS / 64];
    __shared__ float s2[2];
    __shared__ int lastFlag;

    const int p = blockIdx.x * THREADS + threadIdx.x;
    float v = BIG;
    #pragma unroll
    for (int s = 0; s < SEGS; ++s)
        v = fminf(v, pmin[(size_t)s * TOTAL_PTS + p]);
    float r = sqrtf(fmaxf(v, 0.0f) + EPS);

    #pragma unroll
    for (int off = 32; off; off >>= 1) r += __shfl_down(r, off, 64);
    if ((threadIdx.x & 63) == 0) wsum[threadIdx.x >> 6] = r;
    __syncthreads();
    if (threadIdx.x == 0) {
        bsum[blockIdx.x] = (wsum[0] + wsum[1]) + (wsum[2] + wsum[3]);
        __threadfence();                       // make bsum visible device-wide
        unsigned prev = atomicAdd(cnt, 1u);    // device-scope
        lastFlag = (prev == PASS2_BLOCKS - 1);
    }
    __syncthreads();

    if (lastFlag && threadIdx.x < PASS2_BLOCKS) {
        __threadfence();                       // acquire side of the handoff
        float v2 = ((volatile const float*)bsum)[threadIdx.x];
        #pragma unroll
        for (int off = 32; off; off >>= 1) v2 += __shfl_down(v2, off, 64);
        if ((threadIdx.x & 63) == 0) s2[threadIdx.x >> 6] = v2;
    }
    __syncthreads();
    if (lastFlag && threadIdx.x == 0)
        out[0] = (s2[0] + s2[1]) * (1.0f / (float)(BATCH * NPTS));
}

extern "C" void kernel_launch(void* const* d_in, const int* in_sizes, int n_in,
                              void* d_out, int out_size, void* d_ws, size_t ws_size,
                              hipStream_t stream) {
    const float* pred = (const float*)d_in[0];
    const float* gt   = (const float*)d_in[1];
    float* out  = (float*)d_out;
    float* pmin = (float*)d_ws;              // 4MB partial d2 mins (all slots written)
    float* bsum = pmin + PMIN_FLOATS;        // 128 block sums
    unsigned* cnt = (unsigned*)(bsum + PASS2_BLOCKS);  // completion counter

    chamfer_pass1<<<PASS1_BLOCKS, THREADS, 0, stream>>>(pred, gt, pmin, cnt);
    chamfer_pass2<<<PASS2_BLOCKS, THREADS, 0, stream>>>(pmin, bsum, cnt, out);
}

// Round 3
// 70.490 us; speedup vs baseline: 1.0535x; 1.0535x over previous
//
#include <hip/hip_runtime.h>
#include <math.h>

// Problem: predict_pc 4x3x4096, gt_pc 4x3x4096 fp32; symmetric 1-NN chamfer mean.
// Inner-loop math: min d2 = p2+g2-2*p.g  <=>  max score = p.g - g2/2.
// Candidates staged in LDS as float4 (x, y, z, -g2/2) -> 3 fma + 1 max per pair.
// R6: REVERT to R0 (best measured: 70.6/71.1us). R4 regrid (72.9) and R5 pk_fma
// (74.3) both null-to-negative: total time is dominated by harness poison fill
// (40.4us @ 83% HBM peak) + reset overhead (~20us); kernel compute (~8-10us) is
// below the measurement noise floor. Keeping the empirically best artifact.
#define BATCH 4
#define NPTS 4096
#define THREADS 256
#define P 8                          // points per thread
#define SEGS 32                      // candidate segments
#define CSEG (NPTS / SEGS)           // 128 candidates per segment
#define PTGRPS (NPTS / (THREADS * P))        // 2 point-groups per (dir,batch)
#define PASS1_BLOCKS (2 * BATCH * PTGRPS * SEGS)  // 512 -> 2 blocks/CU, 8 waves/CU
#define TOTAL_PTS (2 * BATCH * NPTS)         // 32768
#define PASS2_BLOCKS 128                     // one point per thread

#define EPS 1e-8f
#define BIG 1e30f

// ws layout: [0 .. SEGS*TOTAL_PTS) partial d2 mins (4MB); then PASS2_BLOCKS sums.
#define PMIN_FLOATS ((size_t)SEGS * TOTAL_PTS)

__global__ __launch_bounds__(THREADS) void chamfer_pass1(
    const float* __restrict__ pred, const float* __restrict__ gt,
    float* __restrict__ pmin)
{
    __shared__ float4 lc[CSEG];   // (x, y, z, -0.5*g2) per candidate

    const int bid   = blockIdx.x;
    const int seg   = bid & (SEGS - 1);
    const int ptgrp = (bid >> 5) & (PTGRPS - 1);
    const int batch = (bid >> 6) & (BATCH - 1);
    const int dir   = bid >> 8;

    const float* pts  = (dir == 0) ? pred : gt;
    const float* cand = (dir == 0) ? gt   : pred;

    // Stage this segment's 128 candidates (threads 0..127), computing -g2/2.
    if (threadIdx.x < CSEG) {
        const float* cb = cand + (size_t)batch * 3 * NPTS + seg * CSEG;
        const float x = cb[threadIdx.x];
        const float y = cb[NPTS + threadIdx.x];
        const float z = cb[2 * NPTS + threadIdx.x];
        const float s = -0.5f * fmaf(x, x, fmaf(y, y, z * z));
        lc[threadIdx.x] = make_float4(x, y, z, s);
    }
    __syncthreads();

    // This thread's 8 points (coalesced, stride-256 within the 2048-pt group).
    const float* pb = pts + (size_t)batch * 3 * NPTS;
    const int pbase = ptgrp * (THREADS * P) + threadIdx.x;
    float px[P], py[P], pz[P], smax[P];
    #pragma unroll
    for (int k = 0; k < P; ++k) {
        const int i = pbase + k * THREADS;
        px[k] = pb[i];
        py[k] = pb[NPTS + i];
        pz[k] = pb[2 * NPTS + i];
        smax[k] = -BIG;
    }

    // 32 groups of 4 candidates: 4 ds_read_b128 (broadcast) + 4*P*(3 fma)
    // + P max3-tree per group. unroll 4 keeps >=2 groups of LDS reads in flight.
    #pragma unroll 4
    for (int g = 0; g < CSEG / 4; ++g) {
        const float4 c0 = lc[4 * g + 0];
        const float4 c1 = lc[4 * g + 1];
        const float4 c2 = lc[4 * g + 2];
        const float4 c3 = lc[4 * g + 3];
        #pragma unroll
        for (int k = 0; k < P; ++k) {
            float t0 = fmaf(px[k], c0.x, fmaf(py[k], c0.y, fmaf(pz[k], c0.z, c0.w)));
            float t1 = fmaf(px[k], c1.x, fmaf(py[k], c1.y, fmaf(pz[k], c1.z, c1.w)));
            float t2 = fmaf(px[k], c2.x, fmaf(py[k], c2.y, fmaf(pz[k], c2.z, c2.w)));
            float t3 = fmaf(px[k], c3.x, fmaf(py[k], c3.y, fmaf(pz[k], c3.z, c3.w)));
            // v_max3-friendly tree: max3(t0,t1,t2), then max3(that,t3,smax)
            smax[k] = fmaxf(fmaxf(fmaxf(t0, t1), t2), fmaxf(t3, smax[k]));
        }
    }

    // Convert back to d2 and store: pmin[seg][global_point], coalesced per k.
    const int gp = dir * (BATCH * NPTS) + batch * NPTS + pbase;
    #pragma unroll
    for (int k = 0; k < P; ++k) {
        const float p2 = fmaf(px[k], px[k], fmaf(py[k], py[k], pz[k] * pz[k]));
        pmin[(size_t)seg * TOTAL_PTS + gp + k * THREADS] = fmaf(-2.0f, smax[k], p2);
    }
}

// Pass 2: one point per thread; min over 32 segment d2s, clamp, sqrt(+eps), block-sum.
__global__ __launch_bounds__(THREADS) void chamfer_pass2(
    const float* __restrict__ pmin, float* __restrict__ bsum)
{
    const int p = blockIdx.x * THREADS + threadIdx.x;
    float v = BIG;
    #pragma unroll
    for (int s = 0; s < SEGS; ++s)
        v = fminf(v, pmin[(size_t)s * TOTAL_PTS + p]);
    float r = sqrtf(fmaxf(v, 0.0f) + EPS);

    #pragma unroll
    for (int off = 32; off; off >>= 1) r += __shfl_down(r, off, 64);
    __shared__ float wsum[THREADS / 64];
    if ((threadIdx.x & 63) == 0) wsum[threadIdx.x >> 6] = r;
    __syncthreads();
    if (threadIdx.x == 0)
        bsum[blockIdx.x] = (wsum[0] + wsum[1]) + (wsum[2] + wsum[3]);
}

// Pass 3: reduce 128 block sums; both means share denominator B*NPTS = 16384.
__global__ void chamfer_pass3(const float* __restrict__ bsum, float* __restrict__ out)
{
    float v = bsum[threadIdx.x];
    #pragma unroll
    for (int off = 32; off; off >>= 1) v += __shfl_down(v, off, 64);
    __shared__ float s[2];
    if ((threadIdx.x & 63) == 0) s[threadIdx.x >> 6] = v;
    __syncthreads();
    if (threadIdx.x == 0)
        out[0] = (s[0] + s[1]) * (1.0f / (float)(BATCH * NPTS));
}

extern "C" void kernel_launch(void* const* d_in, const int* in_sizes, int n_in,
                              void* d_out, int out_size, void* d_ws, size_t ws_size,
                              hipStream_t stream) {
    const float* pred = (const float*)d_in[0];
    const float* gt   = (const float*)d_in[1];
    float* out  = (float*)d_out;
    float* pmin = (float*)d_ws;              // 4MB partial d2 mins (all slots written)
    float* bsum = pmin + PMIN_FLOATS;        // 128 block sums

    chamfer_pass1<<<PASS1_BLOCKS, THREADS, 0, stream>>>(pred, gt, pmin);
    chamfer_pass2<<<PASS2_BLOCKS, THREADS, 0, stream>>>(pmin, bsum);
    chamfer_pass3<<<1, 128, 0, stream>>>(bsum, out);
}